// Round 14
// baseline (132.479 us; speedup 1.0000x reference)
//
#include <hip/hip_runtime.h>
#include <hip/hip_bf16.h>

// Problem constants (from reference)
#define BQ 4
#define NN 10000
#define EE 160000
#define HC 256      // H*OUT
#define SLOPEK 0.2f
#define CAPE 128    // padded CSR slots per node (deg avg 16, max ~40)

typedef __attribute__((ext_vector_type(8))) short bf16x8;
typedef __attribute__((ext_vector_type(4))) float f32x4;
typedef __attribute__((ext_vector_type(2))) float f32x2;

// float -> bf16 (RNE)
__device__ __forceinline__ unsigned short f2bf(float f) {
    unsigned int u = __float_as_uint(f);
    u = (u + 0x7FFFu + ((u >> 16) & 1u)) >> 16;
    return (unsigned short)u;
}
__device__ __forceinline__ f32x2 bf2(unsigned int u) {
    return (f32x2){__uint_as_float(u << 16), __uint_as_float(u & 0xFFFF0000u)};
}

// async global->LDS DMA, 16B per lane; dest = lds base + lane*16
__device__ __forceinline__ void gload_lds16(const unsigned short* g, unsigned short* l) {
    __builtin_amdgcn_global_load_lds(
        (const __attribute__((address_space(1))) unsigned int*)g,
        (__attribute__((address_space(3))) unsigned int*)l,
        16, 0, 0);
}

// ---- Kernel W: pack [Wl|Wr] into per-lane MFMA B-fragment layout (bf16),
//      and [bl|br] into bp[512].
__global__ __launch_bounds__(256) void k_wpack(
    const float* __restrict__ Wl, const float* __restrict__ bl,
    const float* __restrict__ Wr, const float* __restrict__ br,
    unsigned short* __restrict__ wp, float* __restrict__ bp)
{
    const int tid = blockIdx.x * 256 + threadIdx.x;
    if (tid < 32768) {
        const int j  = tid & 7;
        const int l  = (tid >> 3) & 63;
        const int s  = (tid >> 9) & 1;
        const int ct = tid >> 10;
        const int col = ct * 16 + (l & 15);
        const int kk  = s * 32 + ((l >> 4) << 3) + j;
        const float w = (col < 256) ? Wl[kk * 256 + col] : Wr[kk * 256 + (col - 256)];
        wp[tid] = f2bf(w);
    } else if (tid < 32768 + 512) {
        const int c = tid - 32768;
        bp[c] = (c < 256) ? bl[c] : br[c - 256];
    }
}

// ---- Kernel A: MFMA lin, LDS-staged coalesced stores.
//      [40000 x 64] @ [64 x 512] -> xl/xr bf16, layout [n][b][256].
__global__ __launch_bounds__(256) void k_lin(
    const float* __restrict__ x, const unsigned short* __restrict__ wp,
    const float* __restrict__ bp,
    unsigned short* __restrict__ xl, unsigned short* __restrict__ xr)
{
    __shared__ unsigned short st[64][264];   // 33.8 KB; pad -> 16B-aligned rows

    const int t = threadIdx.x;
    const int w = t >> 6, l = t & 63;
    const int row0 = blockIdx.x * 64 + w * 16;
    const int arow = row0 + (l & 15);
    const float* xp = x + (size_t)arow * 64 + ((l >> 4) << 3);

    bf16x8 a[2];
#pragma unroll
    for (int s = 0; s < 2; ++s) {
        const float4 lo = *reinterpret_cast<const float4*>(xp + s * 32);
        const float4 hi = *reinterpret_cast<const float4*>(xp + s * 32 + 4);
        union { bf16x8 v; unsigned short u[8]; } tt;
        tt.u[0] = f2bf(lo.x); tt.u[1] = f2bf(lo.y); tt.u[2] = f2bf(lo.z); tt.u[3] = f2bf(lo.w);
        tt.u[4] = f2bf(hi.x); tt.u[5] = f2bf(hi.y); tt.u[6] = f2bf(hi.z); tt.u[7] = f2bf(hi.w);
        a[s] = tt.v;
    }
    const int colb = l & 15;
    const int rsub = (l >> 4) << 2;

    for (int h = 0; h < 2; ++h) {          // h=0: xl (ct 0..15), h=1: xr (ct 16..31)
        for (int g4 = 0; g4 < 4; ++g4) {
            f32x4 acc[4] = {{0.f,0.f,0.f,0.f},{0.f,0.f,0.f,0.f},
                            {0.f,0.f,0.f,0.f},{0.f,0.f,0.f,0.f}};
#pragma unroll
            for (int c = 0; c < 4; ++c) {
                const int ct = h * 16 + g4 * 4 + c;
                const bf16x8 b0 = *reinterpret_cast<const bf16x8*>(wp + (((ct * 2 + 0) * 64 + l) << 3));
                const bf16x8 b1 = *reinterpret_cast<const bf16x8*>(wp + (((ct * 2 + 1) * 64 + l) << 3));
                acc[c] = __builtin_amdgcn_mfma_f32_16x16x32_bf16(a[0], b0, acc[c], 0, 0, 0);
                acc[c] = __builtin_amdgcn_mfma_f32_16x16x32_bf16(a[1], b1, acc[c], 0, 0, 0);
            }
#pragma unroll
            for (int c = 0; c < 4; ++c) {
                const int colh = (g4 * 4 + c) * 16 + colb;   // 0..255 within half
                const float bv = bp[h * 256 + colh];
#pragma unroll
                for (int r = 0; r < 4; ++r)
                    st[w * 16 + rsub + r][colh] = f2bf(acc[c][r] + bv);
            }
        }
        __syncthreads();
        // coalesced write-out: each row = 512 B contiguous (32 lanes x 16 B)
        unsigned short* __restrict__ dstb = h ? xr : xl;
        for (int rr = (t >> 5); rr < 64; rr += 8) {
            const int row = blockIdx.x * 64 + rr;            // row = b*NN + n
            const int bb = row / NN;
            const int n = row - bb * NN;
            const uint4 v = *reinterpret_cast<const uint4*>(&st[rr][(t & 31) * 8]);
            *reinterpret_cast<uint4*>(dstb + (((size_t)(n * 4 + bb)) << 8) + (t & 31) * 8) = v;
        }
        __syncthreads();
    }
}

// ---- Kernel B: edge scatter into padded CSR (no LDS -> full occupancy) ----
__global__ __launch_bounds__(256) void k_edges(
    const int* __restrict__ ei, const float* __restrict__ ea,
    int* __restrict__ cnt, float* __restrict__ asum,
    int2* __restrict__ cmeta)
{
    const int e = blockIdx.x * 256 + threadIdx.x;   // exactly EE threads
    const int   sn = ei[e];
    const int   d  = ei[EE + e];
    const float a  = ea[e];
    const int pos  = atomicAdd(&cnt[d], 1);
    atomicAdd(&asum[d], a);
    if (pos < CAPE - 1)
        cmeta[d * CAPE + pos] = make_int2(sn << 10, __float_as_int(a));
}

// ------ Kernel C: wave = (node, batch-pair); 8-deep global_load_lds DMA ring.
// wave id W = blockIdx*4+wv; n = W>>1, bp = W&1 (batches 2bp, 2bp+1).
// Lane ln: b = 2*bp + (ln>>5); owns channels [(ln&31)*8, +8).
// Per edge the wave DMAs a 1KB half-row into its private LDS ring slot
// (zero VGPR cost -> compiler cannot collapse the pipeline), with explicit
// s_waitcnt vmcnt(7) enforcing 8 loads in flight. ds_read_b128 conflict-free.
__global__ __launch_bounds__(256) void k_gat(
    const unsigned short* __restrict__ xl, const unsigned short* __restrict__ xr,
    const int* __restrict__ cnt, const float* __restrict__ asum,
    const int2* __restrict__ cmeta,
    const float* __restrict__ We, const float* __restrict__ att,
    const float* __restrict__ bias, float* __restrict__ outp)
{
    __shared__ __align__(16) unsigned short ring[4][8][512];   // 32 KB: wave-private rings

    const int t  = threadIdx.x;
    const int wv = t >> 6, ln = t & 63;
    const int W  = blockIdx.x * 4 + wv;
    const int n  = W >> 1;
    const int bp = W & 1;
    const int b  = bp * 2 + (ln >> 5);
    const int ch0 = (ln & 31) * 8;

    int dg0 = cnt[n];
    if (dg0 > 63) dg0 = 63;             // statistically impossible to clamp
    const int dg = __builtin_amdgcn_readfirstlane(dg0);
    const int2 md0 = cmeta[n * CAPE + ln];   // lane i = edge i
    int   ms = md0.x;                   // pre-shifted src (shorts: src<<10)
    float ma = __int_as_float(md0.y);
    if (ln == dg) {                     // self-loop at lane dg
        ms = n << 10;
        ma = asum[n] / fmaxf((float)dg, 1.0f);
    }
    const int ntot = dg + 1;

    // per-lane constants: channels [ch0, ch0+8) as 4 f32x2
    f32x2 we2[4], at2[4], xr2[4], acc2[4];
    {
        const float4* Wp = reinterpret_cast<const float4*>(We + ch0);
        const float4* Ap = reinterpret_cast<const float4*>(att + ch0);
#pragma unroll
        for (int j = 0; j < 2; ++j) {
            const float4 w4 = Wp[j], a4 = Ap[j];
            we2[2*j+0] = (f32x2){w4.x, w4.y};
            we2[2*j+1] = (f32x2){w4.z, w4.w};
            at2[2*j+0] = (f32x2){a4.x, a4.y};
            at2[2*j+1] = (f32x2){a4.z, a4.w};
        }
        const uint4 r0 = *reinterpret_cast<const uint4*>(
            xr + ((size_t)n << 10) + (b << 8) + ch0);
        xr2[0] = bf2(r0.x); xr2[1] = bf2(r0.y); xr2[2] = bf2(r0.z); xr2[3] = bf2(r0.w);
    }
    const f32x2 km1 = {SLOPEK - 1.f, SLOPEK - 1.f};
    const f32x2 z2  = {0.f, 0.f};
#pragma unroll
    for (int k = 0; k < 4; ++k) acc2[k] = z2;
    float sh = 0.f;

    // per-lane global gather address base: row + bp*1KB + lane*16B
    const unsigned short* __restrict__ xlp = xl + (bp << 9) + ln * 8;

    auto edgeC = [&](const uint4& A, float a0) {
        f32x2 xv2[4];
        xv2[0] = bf2(A.x); xv2[1] = bf2(A.y); xv2[2] = bf2(A.z); xv2[3] = bf2(A.w);

        const f32x2 a02 = {a0, a0};
        f32x2 qa = z2, qb = z2;
#pragma unroll
        for (int j = 0; j < 4; ++j) {
            f32x2 s = xv2[j] + xr2[j];                           // v_pk_add_f32
            f32x2 v = __builtin_elementwise_fma(a02, we2[j], s); // v_pk_fma_f32
            f32x2 vm = __builtin_elementwise_min(v, z2);         // v_pk_min_f32
            v = __builtin_elementwise_fma(km1, vm, v);
            if (j & 1) qb = __builtin_elementwise_fma(v, at2[j], qb);
            else       qa = __builtin_elementwise_fma(v, at2[j], qa);
        }
        const f32x2 q2 = qa + qb;
        float p = q2.x + q2.y;
        // reduce over the 16 lanes of this (b, head) group
        p += __shfl_xor(p, 1);
        p += __shfl_xor(p, 2);
        p += __shfl_xor(p, 4);
        p += __shfl_xor(p, 8);
        const float e = __expf(p);     // logits bounded; softmax shift-invariant
        sh += e;
        const f32x2 e2 = {e, e};
#pragma unroll
        for (int j = 0; j < 4; ++j)
            acc2[j] = __builtin_elementwise_fma(e2, xv2[j], acc2[j]);
    };

    // ---- DMA pipeline ----
    // isolate the ring's vmcnt accounting from all earlier loads
    asm volatile("s_waitcnt vmcnt(0)" ::: "memory");

    // prologue: issue DMAs for edges 0..6 (clamped duplicates harmless)
#pragma unroll
    for (int k = 0; k < 7; ++k) {
        const int ic = k < dg ? k : dg;
        const int s_ = __builtin_amdgcn_readlane(ms, ic);
        gload_lds16(xlp + s_, &ring[wv][k][0]);
    }

    for (int i = 0; i < ntot; ++i) {
        // issue DMA for edge i+7 into slot (i+7)&7
        {
            const int idx = i + 7;
            const int ic = idx < dg ? idx : dg;
            const int s_ = __builtin_amdgcn_readlane(ms, ic);
            gload_lds16(xlp + s_, &ring[wv][(i + 7) & 7][0]);
        }
        // edge i's DMA is the oldest of 8 outstanding -> done after vmcnt(7)
        asm volatile("s_waitcnt vmcnt(7)" ::: "memory");
        const uint4 A = *reinterpret_cast<const uint4*>(&ring[wv][i & 7][ln * 8]);
        const float a0 = __int_as_float(__builtin_amdgcn_readlane(__float_as_int(ma), i));
        edgeC(A, a0);
    }
    // drain before LDS deallocation at block end
    asm volatile("s_waitcnt vmcnt(0)" ::: "memory");

    // ---- epilogue: every (b, ch) owned by exactly this lane ----
    const float inv = 1.0f / sh;
    float* ob = outp + (((size_t)(b * NN + n)) << 8) + ch0;
    const float4* Bp = reinterpret_cast<const float4*>(bias + ch0);
#pragma unroll
    for (int j = 0; j < 2; ++j) {
        const float4 b4 = Bp[j];
        float4 o;
        o.x = fmaf(acc2[2*j+0].x, inv, b4.x);
        o.y = fmaf(acc2[2*j+0].y, inv, b4.y);
        o.z = fmaf(acc2[2*j+1].x, inv, b4.z);
        o.w = fmaf(acc2[2*j+1].y, inv, b4.w);
        reinterpret_cast<float4*>(ob)[j] = o;
    }
}

// -------------------------- launcher --------------------------
extern "C" void kernel_launch(void* const* d_in, const int* in_sizes, int n_in,
                              void* d_out, int out_size, void* d_ws, size_t ws_size,
                              hipStream_t stream)
{
    (void)in_sizes; (void)n_in; (void)out_size; (void)ws_size;
    const float* x    = (const float*)d_in[0];
    const int*   ei   = (const int*)d_in[1];
    const float* ea   = (const float*)d_in[2];
    const float* Wl   = (const float*)d_in[3];
    const float* bl   = (const float*)d_in[4];
    const float* Wr   = (const float*)d_in[5];
    const float* br   = (const float*)d_in[6];
    const float* We   = (const float*)d_in[7];
    const float* att  = (const float*)d_in[8];
    const float* bias = (const float*)d_in[9];
    float* outp = (float*)d_out;

    const size_t R = (size_t)BQ * NN;     // 40000 rows
    unsigned short* xl16 = (unsigned short*)d_ws;          // R*HC bf16
    unsigned short* xr16 = xl16 + R * HC;                  // R*HC bf16
    int*   cnt   = (int*)(xr16 + R * HC);
    float* asum  = (float*)(cnt + NN);
    int2*  cmeta = (int2*)(asum + NN);                     // NN*CAPE int2
    unsigned short* wp = (unsigned short*)(cmeta + (size_t)NN * CAPE);  // 32768 bf16
    float* bp    = (float*)(wp + 32768);                   // 512 f32

    // zero cnt + asum (contiguous 2*NN words) — every call (graph-safe)
    hipMemsetAsync(cnt, 0, sizeof(int) * NN * 2, stream);

    k_wpack<<<130, 256, 0, stream>>>(Wl, bl, Wr, br, wp, bp);
    k_lin  <<<625, 256, 0, stream>>>(x, wp, bp, xl16, xr16);
    k_edges<<<625, 256, 0, stream>>>(ei, ea, cnt, asum, cmeta);
    k_gat  <<<(2 * NN) / 4, 256, 0, stream>>>(xl16, xr16, cnt, asum, cmeta,
                                              We, att, bias, outp);
}

// Round 15
// 97.090 us; speedup vs baseline: 1.3645x; 1.3645x over previous
//
#include <hip/hip_runtime.h>
#include <hip/hip_bf16.h>

// Problem constants (from reference)
#define BQ 4
#define NN 10000
#define EE 160000
#define HC 256      // H*OUT
#define SLOPEK 0.2f
#define CAPE 128    // padded CSR slots per node (deg avg 16, max ~40)

typedef __attribute__((ext_vector_type(8))) short bf16x8;
typedef __attribute__((ext_vector_type(4))) float f32x4;
typedef __attribute__((ext_vector_type(2))) float f32x2;

// float -> bf16 (RNE)
__device__ __forceinline__ unsigned short f2bf(float f) {
    unsigned int u = __float_as_uint(f);
    u = (u + 0x7FFFu + ((u >> 16) & 1u)) >> 16;
    return (unsigned short)u;
}
__device__ __forceinline__ f32x2 bf2(unsigned int u) {
    return (f32x2){__uint_as_float(u << 16), __uint_as_float(u & 0xFFFF0000u)};
}

// ---- Kernel W: pack [Wl|Wr] into per-lane MFMA B-fragment layout (bf16),
//      [bl|br] into bp[512]; blocks >=130 zero cnt+asum (fused memset).
__global__ __launch_bounds__(256) void k_wpack(
    const float* __restrict__ Wl, const float* __restrict__ bl,
    const float* __restrict__ Wr, const float* __restrict__ br,
    unsigned short* __restrict__ wp, float* __restrict__ bp,
    int* __restrict__ zbase)
{
    if (blockIdx.x >= 130) {
        const int i = (blockIdx.x - 130) * 256 + threadIdx.x;
        if (i < 2 * NN) zbase[i] = 0;
        return;
    }
    const int tid = blockIdx.x * 256 + threadIdx.x;
    if (tid < 32768) {
        const int j  = tid & 7;
        const int l  = (tid >> 3) & 63;
        const int s  = (tid >> 9) & 1;
        const int ct = tid >> 10;
        const int col = ct * 16 + (l & 15);
        const int kk  = s * 32 + ((l >> 4) << 3) + j;
        const float w = (col < 256) ? Wl[kk * 256 + col] : Wr[kk * 256 + (col - 256)];
        wp[tid] = f2bf(w);
    } else if (tid < 32768 + 512) {
        const int c = tid - 32768;
        bp[c] = (c < 256) ? bl[c] : br[c - 256];
    }
}

// ---- Fused prep: blocks [0,625) = MFMA lin (LDS-staged coalesced stores);
//      blocks [625,1250) = edge scatter.
//      xl/xr layout: natural row-major [b*NN+n][256] bf16.
__global__ __launch_bounds__(256) void k_pre(
    const float* __restrict__ x, const unsigned short* __restrict__ wp,
    const float* __restrict__ bp,
    unsigned short* __restrict__ xl, unsigned short* __restrict__ xr,
    const int* __restrict__ ei, const float* __restrict__ ea,
    int* __restrict__ cnt, float* __restrict__ asum,
    int* __restrict__ cmeta)
{
    __shared__ unsigned short st[64][264];   // 33.8 KB; pad -> 16B-aligned rows

    if (blockIdx.x >= 625) {
        // ---- edge scatter into padded CSR; packed (src<<16 | bf16(attr)) ----
        const int e = (blockIdx.x - 625) * 256 + threadIdx.x;   // exactly EE threads
        const int   sn = ei[e];
        const int   d  = ei[EE + e];
        const float a  = ea[e];
        const int pos  = atomicAdd(&cnt[d], 1);
        atomicAdd(&asum[d], a);
        if (pos < CAPE - 1)
            cmeta[d * CAPE + pos] = (sn << 16) | (int)f2bf(a);
        return;
    }
    // ---- MFMA lin: [40000 x 64] @ [64 x 512] -> xl/xr bf16, row-major.
    const int t = threadIdx.x;
    const int w = t >> 6, l = t & 63;
    const int row0 = blockIdx.x * 64 + w * 16;
    const int arow = row0 + (l & 15);
    const float* xp = x + (size_t)arow * 64 + ((l >> 4) << 3);

    bf16x8 a[2];
#pragma unroll
    for (int s = 0; s < 2; ++s) {
        const float4 lo = *reinterpret_cast<const float4*>(xp + s * 32);
        const float4 hi = *reinterpret_cast<const float4*>(xp + s * 32 + 4);
        union { bf16x8 v; unsigned short u[8]; } tt;
        tt.u[0] = f2bf(lo.x); tt.u[1] = f2bf(lo.y); tt.u[2] = f2bf(lo.z); tt.u[3] = f2bf(lo.w);
        tt.u[4] = f2bf(hi.x); tt.u[5] = f2bf(hi.y); tt.u[6] = f2bf(hi.z); tt.u[7] = f2bf(hi.w);
        a[s] = tt.v;
    }
    const int colb = l & 15;
    const int rsub = (l >> 4) << 2;

    for (int h = 0; h < 2; ++h) {          // h=0: xl (ct 0..15), h=1: xr (ct 16..31)
        for (int g4 = 0; g4 < 4; ++g4) {
            f32x4 acc[4] = {{0.f,0.f,0.f,0.f},{0.f,0.f,0.f,0.f},
                            {0.f,0.f,0.f,0.f},{0.f,0.f,0.f,0.f}};
#pragma unroll
            for (int c = 0; c < 4; ++c) {
                const int ct = h * 16 + g4 * 4 + c;
                const bf16x8 b0 = *reinterpret_cast<const bf16x8*>(wp + (((ct * 2 + 0) * 64 + l) << 3));
                const bf16x8 b1 = *reinterpret_cast<const bf16x8*>(wp + (((ct * 2 + 1) * 64 + l) << 3));
                acc[c] = __builtin_amdgcn_mfma_f32_16x16x32_bf16(a[0], b0, acc[c], 0, 0, 0);
                acc[c] = __builtin_amdgcn_mfma_f32_16x16x32_bf16(a[1], b1, acc[c], 0, 0, 0);
            }
#pragma unroll
            for (int c = 0; c < 4; ++c) {
                const int colh = (g4 * 4 + c) * 16 + colb;   // 0..255 within half
                const float bv = bp[h * 256 + colh];
#pragma unroll
                for (int r = 0; r < 4; ++r)
                    st[w * 16 + rsub + r][colh] = f2bf(acc[c][r] + bv);
            }
        }
        __syncthreads();
        // coalesced write-out: each row = 512 B contiguous (32 lanes x 16 B)
        unsigned short* __restrict__ dstb = h ? xr : xl;
        for (int rr = (t >> 5); rr < 64; rr += 8) {
            const size_t row = blockIdx.x * 64 + rr;         // row = b*NN + n
            const uint4 v = *reinterpret_cast<const uint4*>(&st[rr][(t & 31) * 8]);
            *reinterpret_cast<uint4*>(dstb + (row << 8) + (t & 31) * 8) = v;
        }
        __syncthreads();
    }
}

// ------ Kernel C: wave = (node, single batch); batch = blockIdx & 3. ------
// XCD sharding: with XCD = blockIdx % 8 round-robin, batch b runs only on
// XCDs {b, b+4} -> per-XCD xl working set 5.1 MB (mostly L2-resident).
// Lane ln owns channels [ln*4, ln*4+4); head = ln>>5; 5-step butterfly.
// Per edge the wave loads a 512B row slice (uint2/lane); meta via readlane
// (packed src|bf16attr); 4-slot (3-ahead) pipeline; packed-f32 math.
__global__ __launch_bounds__(256) void k_gat(
    const unsigned short* __restrict__ xl, const unsigned short* __restrict__ xr,
    const int* __restrict__ cnt, const float* __restrict__ asum,
    const int* __restrict__ cmeta,
    const float* __restrict__ We, const float* __restrict__ att,
    const float* __restrict__ bias, float* __restrict__ outp)
{
    const int t  = threadIdx.x;
    const int wv = t >> 6, ln = t & 63;
    const int batch = blockIdx.x & 3;
    const int n  = (blockIdx.x >> 2) * 4 + wv;
    const int ch0 = ln * 4;

    int dg0 = cnt[n];
    if (dg0 > 63) dg0 = 63;             // statistically impossible to clamp
    const int dg = __builtin_amdgcn_readfirstlane(dg0);
    int mp = cmeta[n * CAPE + ln];      // lane i = edge i (src<<16 | bf16 attr)
    if (ln == dg)                       // self-loop at lane dg
        mp = (n << 16) | (int)f2bf(asum[n] / fmaxf((float)dg, 1.0f));
    const int ntot = dg + 1;

    // per-lane constants: channels [ch0, ch0+4) as 2 f32x2
    f32x2 we2[2], at2[2], xr2[2], acc2[2];
    {
        const float4 w4 = *reinterpret_cast<const float4*>(We + ch0);
        const float4 a4 = *reinterpret_cast<const float4*>(att + ch0);
        we2[0] = (f32x2){w4.x, w4.y}; we2[1] = (f32x2){w4.z, w4.w};
        at2[0] = (f32x2){a4.x, a4.y}; at2[1] = (f32x2){a4.z, a4.w};
        const uint2 r0 = *reinterpret_cast<const uint2*>(
            xr + (((size_t)(batch * NN + n)) << 8) + ch0);
        xr2[0] = bf2(r0.x); xr2[1] = bf2(r0.y);
    }
    const f32x2 km1 = {SLOPEK - 1.f, SLOPEK - 1.f};
    const f32x2 z2  = {0.f, 0.f};
    acc2[0] = z2; acc2[1] = z2;
    float sh = 0.f;

    // per-lane gather base within this batch's table
    const unsigned short* __restrict__ xlb = xl + (((size_t)batch * NN) << 8) + ch0;

    // pipeline slots (registers, statically indexed)
    uint2 A0, A1, A2, A3;
    float ea0, ea1, ea2, ea3;

#define LOADSLOT(S, IDX) do { \
        const int ii_ = (IDX); \
        const int ic_ = ii_ < dg ? ii_ : dg; \
        const int sc_ = __builtin_amdgcn_readlane(mp, ic_); \
        ea##S = __uint_as_float(((unsigned int)sc_) << 16); \
        A##S = *reinterpret_cast<const uint2*>(xlb + ((size_t)(sc_ >> 16) << 8)); \
    } while (0)

    auto edgeC = [&](const uint2& A, float a0) {
        f32x2 xv2[2];
        xv2[0] = bf2(A.x); xv2[1] = bf2(A.y);

        const f32x2 a02 = {a0, a0};
        f32x2 q2 = z2;
#pragma unroll
        for (int j = 0; j < 2; ++j) {
            f32x2 s = xv2[j] + xr2[j];                           // v_pk_add_f32
            f32x2 v = __builtin_elementwise_fma(a02, we2[j], s); // v_pk_fma_f32
            f32x2 vm = __builtin_elementwise_min(v, z2);         // v_pk_min_f32
            v = __builtin_elementwise_fma(km1, vm, v);
            q2 = __builtin_elementwise_fma(v, at2[j], q2);
        }
        float p = q2.x + q2.y;
        // reduce over the 32 lanes of this head group (halves stay closed)
        p += __shfl_xor(p, 1);
        p += __shfl_xor(p, 2);
        p += __shfl_xor(p, 4);
        p += __shfl_xor(p, 8);
        p += __shfl_xor(p, 16);
        const float e = __expf(p);     // logits bounded; softmax shift-invariant
        sh += e;
        const f32x2 e2 = {e, e};
        acc2[0] = __builtin_elementwise_fma(e2, xv2[0], acc2[0]);
        acc2[1] = __builtin_elementwise_fma(e2, xv2[1], acc2[1]);
    };

    // prologue: edges 0..2 (clamped duplicates harmless)
    LOADSLOT(0, 0);
    LOADSLOT(1, 1);
    LOADSLOT(2, 2);

    int i = 0;
    for (; i + 3 < ntot; i += 4) {
        LOADSLOT(3, i + 3); edgeC(A0, ea0);
        LOADSLOT(0, i + 4); edgeC(A1, ea1);
        LOADSLOT(1, i + 5); edgeC(A2, ea2);
        LOADSLOT(2, i + 6); edgeC(A3, ea3);
    }
    // tail (slots 0..2 hold edges i..i+2); wave-uniform branches
    if (i     < ntot) edgeC(A0, ea0);
    if (i + 1 < ntot) edgeC(A1, ea1);
    if (i + 2 < ntot) edgeC(A2, ea2);
#undef LOADSLOT

    // ---- epilogue: lane owns channels [ch0, ch0+4) of (batch, n) ----
    const float inv = 1.0f / sh;
    const float4 b4 = *reinterpret_cast<const float4*>(bias + ch0);
    float4 o;
    o.x = fmaf(acc2[0].x, inv, b4.x);
    o.y = fmaf(acc2[0].y, inv, b4.y);
    o.z = fmaf(acc2[1].x, inv, b4.z);
    o.w = fmaf(acc2[1].y, inv, b4.w);
    *reinterpret_cast<float4*>(outp + (((size_t)(batch * NN + n)) << 8) + ch0) = o;
}

// -------------------------- launcher --------------------------
extern "C" void kernel_launch(void* const* d_in, const int* in_sizes, int n_in,
                              void* d_out, int out_size, void* d_ws, size_t ws_size,
                              hipStream_t stream)
{
    (void)in_sizes; (void)n_in; (void)out_size; (void)ws_size;
    const float* x    = (const float*)d_in[0];
    const int*   ei   = (const int*)d_in[1];
    const float* ea   = (const float*)d_in[2];
    const float* Wl   = (const float*)d_in[3];
    const float* bl   = (const float*)d_in[4];
    const float* Wr   = (const float*)d_in[5];
    const float* br   = (const float*)d_in[6];
    const float* We   = (const float*)d_in[7];
    const float* att  = (const float*)d_in[8];
    const float* bias = (const float*)d_in[9];
    float* outp = (float*)d_out;

    const size_t R = (size_t)BQ * NN;     // 40000 rows
    unsigned short* xl16 = (unsigned short*)d_ws;          // R*HC bf16
    unsigned short* xr16 = xl16 + R * HC;                  // R*HC bf16
    int*   cnt   = (int*)(xr16 + R * HC);
    float* asum  = (float*)(cnt + NN);
    int*   cmeta = (int*)(asum + NN);                      // NN*CAPE int
    unsigned short* wp = (unsigned short*)(cmeta + (size_t)NN * CAPE);  // 32768 bf16
    float* bp    = (float*)(wp + 32768);                   // 512 f32

    // k_wpack also zeroes cnt+asum (blocks >= 130)
    k_wpack<<<130 + (2 * NN + 255) / 256, 256, 0, stream>>>(Wl, bl, Wr, br, wp, bp, cnt);
    k_pre  <<<1250, 256, 0, stream>>>(x, wp, bp, xl16, xr16,
                                      ei, ea, cnt, asum, cmeta);
    k_gat  <<<NN, 256, 0, stream>>>(xl16, xr16, cnt, asum, cmeta,
                                    We, att, bias, outp);
}

// Round 16
// 89.088 us; speedup vs baseline: 1.4871x; 1.0898x over previous
//
#include <hip/hip_runtime.h>
#include <hip/hip_bf16.h>

// Problem constants (from reference)
#define BQ 4
#define NN 10000
#define EE 160000
#define HC 256      // H*OUT
#define SLOPEK 0.2f
#define CAPE 64     // padded CSR slots per node (deg avg 16, max ~40)

typedef __attribute__((ext_vector_type(8))) short bf16x8;
typedef __attribute__((ext_vector_type(4))) float f32x4;
typedef __attribute__((ext_vector_type(2))) float f32x2;

// float -> bf16 (RNE)
__device__ __forceinline__ unsigned short f2bf(float f) {
    unsigned int u = __float_as_uint(f);
    u = (u + 0x7FFFu + ((u >> 16) & 1u)) >> 16;
    return (unsigned short)u;
}
__device__ __forceinline__ f32x2 bf2(unsigned int u) {
    return (f32x2){__uint_as_float(u << 16), __uint_as_float(u & 0xFFFF0000u)};
}

// ---- Kernel W: pack [Wl|Wr] into per-lane MFMA B-fragment layout (bf16),
//      [bl|br] into bp[512]; blocks >=130 zero cnt+asum (fused memset).
__global__ __launch_bounds__(256) void k_wpack(
    const float* __restrict__ Wl, const float* __restrict__ bl,
    const float* __restrict__ Wr, const float* __restrict__ br,
    unsigned short* __restrict__ wp, float* __restrict__ bp,
    int* __restrict__ zbase)
{
    if (blockIdx.x >= 130) {
        const int i = (blockIdx.x - 130) * 256 + threadIdx.x;
        if (i < 2 * NN) zbase[i] = 0;
        return;
    }
    const int tid = blockIdx.x * 256 + threadIdx.x;
    if (tid < 32768) {
        const int j  = tid & 7;
        const int l  = (tid >> 3) & 63;
        const int s  = (tid >> 9) & 1;
        const int ct = tid >> 10;
        const int col = ct * 16 + (l & 15);
        const int kk  = s * 32 + ((l >> 4) << 3) + j;
        const float w = (col < 256) ? Wl[kk * 256 + col] : Wr[kk * 256 + (col - 256)];
        wp[tid] = f2bf(w);
    } else if (tid < 32768 + 512) {
        const int c = tid - 32768;
        bp[c] = (c < 256) ? bl[c] : br[c - 256];
    }
}

// ---- Fused prep: blocks [0,625) = MFMA lin (LDS-staged coalesced stores);
//      blocks [625,1250) = edge scatter.
//      xl/xr layout: natural row-major [b*NN+n][256] bf16.
__global__ __launch_bounds__(256) void k_pre(
    const float* __restrict__ x, const unsigned short* __restrict__ wp,
    const float* __restrict__ bp,
    unsigned short* __restrict__ xl, unsigned short* __restrict__ xr,
    const int* __restrict__ ei, const float* __restrict__ ea,
    int* __restrict__ cnt, float* __restrict__ asum,
    int* __restrict__ cmeta)
{
    __shared__ unsigned short st[64][264];   // 33.8 KB; pad -> 16B-aligned rows

    if (blockIdx.x >= 625) {
        // ---- edge scatter into padded CSR; packed (src<<16 | bf16(attr)) ----
        const int e = (blockIdx.x - 625) * 256 + threadIdx.x;   // exactly EE threads
        const int   sn = ei[e];
        const int   d  = ei[EE + e];
        const float a  = ea[e];
        const int pos  = atomicAdd(&cnt[d], 1);
        atomicAdd(&asum[d], a);
        if (pos < CAPE - 1)
            cmeta[d * CAPE + pos] = (sn << 16) | (int)f2bf(a);
        return;
    }
    // ---- MFMA lin: [40000 x 64] @ [64 x 512] -> xl/xr bf16, row-major.
    const int t = threadIdx.x;
    const int w = t >> 6, l = t & 63;
    const int row0 = blockIdx.x * 64 + w * 16;
    const int arow = row0 + (l & 15);
    const float* xp = x + (size_t)arow * 64 + ((l >> 4) << 3);

    bf16x8 a[2];
#pragma unroll
    for (int s = 0; s < 2; ++s) {
        const float4 lo = *reinterpret_cast<const float4*>(xp + s * 32);
        const float4 hi = *reinterpret_cast<const float4*>(xp + s * 32 + 4);
        union { bf16x8 v; unsigned short u[8]; } tt;
        tt.u[0] = f2bf(lo.x); tt.u[1] = f2bf(lo.y); tt.u[2] = f2bf(lo.z); tt.u[3] = f2bf(lo.w);
        tt.u[4] = f2bf(hi.x); tt.u[5] = f2bf(hi.y); tt.u[6] = f2bf(hi.z); tt.u[7] = f2bf(hi.w);
        a[s] = tt.v;
    }
    const int colb = l & 15;
    const int rsub = (l >> 4) << 2;

    for (int h = 0; h < 2; ++h) {          // h=0: xl (ct 0..15), h=1: xr (ct 16..31)
        for (int g4 = 0; g4 < 4; ++g4) {
            f32x4 acc[4] = {{0.f,0.f,0.f,0.f},{0.f,0.f,0.f,0.f},
                            {0.f,0.f,0.f,0.f},{0.f,0.f,0.f,0.f}};
#pragma unroll
            for (int c = 0; c < 4; ++c) {
                const int ct = h * 16 + g4 * 4 + c;
                const bf16x8 b0 = *reinterpret_cast<const bf16x8*>(wp + (((ct * 2 + 0) * 64 + l) << 3));
                const bf16x8 b1 = *reinterpret_cast<const bf16x8*>(wp + (((ct * 2 + 1) * 64 + l) << 3));
                acc[c] = __builtin_amdgcn_mfma_f32_16x16x32_bf16(a[0], b0, acc[c], 0, 0, 0);
                acc[c] = __builtin_amdgcn_mfma_f32_16x16x32_bf16(a[1], b1, acc[c], 0, 0, 0);
            }
#pragma unroll
            for (int c = 0; c < 4; ++c) {
                const int colh = (g4 * 4 + c) * 16 + colb;   // 0..255 within half
                const float bv = bp[h * 256 + colh];
#pragma unroll
                for (int r = 0; r < 4; ++r)
                    st[w * 16 + rsub + r][colh] = f2bf(acc[c][r] + bv);
            }
        }
        __syncthreads();
        // coalesced write-out: each row = 512 B contiguous (32 lanes x 16 B)
        unsigned short* __restrict__ dstb = h ? xr : xl;
        for (int rr = (t >> 5); rr < 64; rr += 8) {
            const size_t row = blockIdx.x * 64 + rr;         // row = b*NN + n
            const uint4 v = *reinterpret_cast<const uint4*>(&st[rr][(t & 31) * 8]);
            *reinterpret_cast<uint4*>(dstb + (row << 8) + (t & 31) * 8) = v;
        }
        __syncthreads();
    }
}

// ------ Kernel C: wave = (node, batch), 2 edges per pass. ------
// batch = blockIdx & 3 (XCD shard: batch b on XCDs {b, b+4}); n = (bid>>2)*4+wv.
// Lanes 0-31 process edge i, lanes 32-63 edge i+1; lane owns 8 channels
// ch0 = (ln&31)*8 of its edge's row (uint4 load). Head = (ln&15)>=16? no:
// lanes (ln&31)<16 -> head 0, else head 1; 4-step 16-lane butterfly.
// 4 pair-slots = 8 edges in flight. Halves merged once via shfl_xor(32).
__global__ __launch_bounds__(256) void k_gat(
    const unsigned short* __restrict__ xl, const unsigned short* __restrict__ xr,
    const int* __restrict__ cnt, const float* __restrict__ asum,
    const int* __restrict__ cmeta,
    const float* __restrict__ We, const float* __restrict__ att,
    const float* __restrict__ bias, float* __restrict__ outp)
{
    const int t  = threadIdx.x;
    const int wv = t >> 6, ln = t & 63;
    const int batch = blockIdx.x & 3;
    const int n  = (blockIdx.x >> 2) * 4 + wv;
    const int hi = ln >> 5;               // 0: edge i, 1: edge i+1
    const int ch0 = (ln & 31) * 8;

    int dg0 = cnt[n];
    if (dg0 > CAPE - 1) dg0 = CAPE - 1;   // statistically impossible to clamp
    const int dg = __builtin_amdgcn_readfirstlane(dg0);
    int mp = cmeta[n * CAPE + ln];        // lane i = edge i (src<<16 | bf16 attr)
    if (ln == dg)                         // self-loop at lane dg
        mp = (n << 16) | (int)f2bf(asum[n] / fmaxf((float)dg, 1.0f));
    const int ntot = dg + 1;

    // per-lane constants: channels [ch0, ch0+8) as 4 f32x2
    f32x2 we2[4], at2[4], xr2[4], acc2[4];
    {
        const float4* Wp = reinterpret_cast<const float4*>(We + ch0);
        const float4* Ap = reinterpret_cast<const float4*>(att + ch0);
#pragma unroll
        for (int j = 0; j < 2; ++j) {
            const float4 w4 = Wp[j], a4 = Ap[j];
            we2[2*j+0] = (f32x2){w4.x, w4.y};
            we2[2*j+1] = (f32x2){w4.z, w4.w};
            at2[2*j+0] = (f32x2){a4.x, a4.y};
            at2[2*j+1] = (f32x2){a4.z, a4.w};
        }
        const uint4 r0 = *reinterpret_cast<const uint4*>(
            xr + (((size_t)(batch * NN + n)) << 8) + ch0);
        xr2[0] = bf2(r0.x); xr2[1] = bf2(r0.y); xr2[2] = bf2(r0.z); xr2[3] = bf2(r0.w);
    }
    const f32x2 km1 = {SLOPEK - 1.f, SLOPEK - 1.f};
    const f32x2 z2  = {0.f, 0.f};
#pragma unroll
    for (int k = 0; k < 4; ++k) acc2[k] = z2;
    float sh = 0.f;

    // per-lane gather base within this batch's table (+ channel offset)
    const unsigned short* __restrict__ xlb =
        xl + (((size_t)batch * NN) << 8) + ch0;

    // pair-slots (registers, statically indexed); slot S = edges (I, I+1)
    uint4 A0, A1, A2, A3;
    float ea0, ea1, ea2, ea3;

#define LOADSLOT(S, I) do { \
        const int iA_ = (I) < dg ? (I) : dg; \
        const int iB_ = (I) + 1 < dg ? (I) + 1 : dg; \
        const int mA_ = __builtin_amdgcn_readlane(mp, iA_); \
        const int mB_ = __builtin_amdgcn_readlane(mp, iB_); \
        const int mm_ = hi ? mB_ : mA_; \
        ea##S = __uint_as_float(((unsigned int)mm_) << 16); \
        A##S = *reinterpret_cast<const uint4*>(xlb + ((size_t)(mm_ >> 16) << 8)); \
    } while (0)

    auto edgeC = [&](const uint4& A, float a0, int idx) {
        f32x2 xv2[4];
        xv2[0] = bf2(A.x); xv2[1] = bf2(A.y); xv2[2] = bf2(A.z); xv2[3] = bf2(A.w);

        const f32x2 a02 = {a0, a0};
        f32x2 qa = z2, qb = z2;
#pragma unroll
        for (int j = 0; j < 4; ++j) {
            f32x2 s = xv2[j] + xr2[j];                           // v_pk_add_f32
            f32x2 v = __builtin_elementwise_fma(a02, we2[j], s); // v_pk_fma_f32
            f32x2 vm = __builtin_elementwise_min(v, z2);         // v_pk_min_f32
            v = __builtin_elementwise_fma(km1, vm, v);
            if (j & 1) qb = __builtin_elementwise_fma(v, at2[j], qb);
            else       qa = __builtin_elementwise_fma(v, at2[j], qa);
        }
        const f32x2 q2 = qa + qb;
        float p = q2.x + q2.y;
        // reduce over the 16 lanes of this (edge-half, head) group
        p += __shfl_xor(p, 1);
        p += __shfl_xor(p, 2);
        p += __shfl_xor(p, 4);
        p += __shfl_xor(p, 8);
        float e = __expf(p);          // logits bounded; softmax shift-invariant
        if (idx + hi >= ntot) e = 0.f;   // mask invalid second-half edge
        sh += e;
        const f32x2 e2 = {e, e};
#pragma unroll
        for (int j = 0; j < 4; ++j)
            acc2[j] = __builtin_elementwise_fma(e2, xv2[j], acc2[j]);
    };

    // prologue: pairs at 0, 2, 4 (clamped duplicates harmless)
    LOADSLOT(0, 0);
    LOADSLOT(1, 2);
    LOADSLOT(2, 4);

    int i = 0;
    for (; i + 6 < ntot; i += 8) {
        LOADSLOT(3, i + 6);  edgeC(A0, ea0, i);
        LOADSLOT(0, i + 8);  edgeC(A1, ea1, i + 2);
        LOADSLOT(1, i + 10); edgeC(A2, ea2, i + 4);
        LOADSLOT(2, i + 12); edgeC(A3, ea3, i + 6);
    }
    // tail: slots 0..2 hold pairs at i, i+2, i+4; per-lane masks handle odd edges
    if (i     < ntot) edgeC(A0, ea0, i);
    if (i + 2 < ntot) edgeC(A1, ea1, i + 2);
    if (i + 4 < ntot) edgeC(A2, ea2, i + 4);
#undef LOADSLOT

    // ---- merge the two edge-halves (disjoint edge subsets) ----
    sh += __shfl_xor(sh, 32);
#pragma unroll
    for (int j = 0; j < 4; ++j) {
        acc2[j].x += __shfl_xor(acc2[j].x, 32);
        acc2[j].y += __shfl_xor(acc2[j].y, 32);
    }

    // ---- epilogue: lane writes channels ch0 + hi*4 .. +4 ----
    const float inv = 1.0f / sh;
    const f32x2 s0 = hi ? acc2[2] : acc2[0];
    const f32x2 s1 = hi ? acc2[3] : acc2[1];
    const float4 b4 = *reinterpret_cast<const float4*>(bias + ch0 + hi * 4);
    float4 o;
    o.x = fmaf(s0.x, inv, b4.x);
    o.y = fmaf(s0.y, inv, b4.y);
    o.z = fmaf(s1.x, inv, b4.z);
    o.w = fmaf(s1.y, inv, b4.w);
    *reinterpret_cast<float4*>(
        outp + (((size_t)(batch * NN + n)) << 8) + ch0 + hi * 4) = o;
}

// -------------------------- launcher --------------------------
extern "C" void kernel_launch(void* const* d_in, const int* in_sizes, int n_in,
                              void* d_out, int out_size, void* d_ws, size_t ws_size,
                              hipStream_t stream)
{
    (void)in_sizes; (void)n_in; (void)out_size; (void)ws_size;
    const float* x    = (const float*)d_in[0];
    const int*   ei   = (const int*)d_in[1];
    const float* ea   = (const float*)d_in[2];
    const float* Wl   = (const float*)d_in[3];
    const float* bl   = (const float*)d_in[4];
    const float* Wr   = (const float*)d_in[5];
    const float* br   = (const float*)d_in[6];
    const float* We   = (const float*)d_in[7];
    const float* att  = (const float*)d_in[8];
    const float* bias = (const float*)d_in[9];
    float* outp = (float*)d_out;

    const size_t R = (size_t)BQ * NN;     // 40000 rows
    unsigned short* xl16 = (unsigned short*)d_ws;          // R*HC bf16
    unsigned short* xr16 = xl16 + R * HC;                  // R*HC bf16
    int*   cnt   = (int*)(xr16 + R * HC);
    float* asum  = (float*)(cnt + NN);
    int*   cmeta = (int*)(asum + NN);                      // NN*CAPE int
    unsigned short* wp = (unsigned short*)(cmeta + (size_t)NN * CAPE);  // 32768 bf16
    float* bp    = (float*)(wp + 32768);                   // 512 f32

    // k_wpack also zeroes cnt+asum (blocks >= 130)
    k_wpack<<<130 + (2 * NN + 255) / 256, 256, 0, stream>>>(Wl, bl, Wr, br, wp, bp, cnt);
    k_pre  <<<1250, 256, 0, stream>>>(x, wp, bp, xl16, xr16,
                                      ei, ea, cnt, asum, cmeta);
    k_gat  <<<NN, 256, 0, stream>>>(xl16, xr16, cnt, asum, cmeta,
                                    We, att, bias, outp);
}

// Round 17
// 86.377 us; speedup vs baseline: 1.5337x; 1.0314x over previous
//
#include <hip/hip_runtime.h>
#include <hip/hip_bf16.h>

// Problem constants (from reference)
#define BQ 4
#define NN 10000
#define EE 160000
#define HC 256      // H*OUT
#define SLOPEK 0.2f
#define CAPE 64     // padded CSR slots per node (deg avg 16, max ~40)

typedef __attribute__((ext_vector_type(8))) short bf16x8;
typedef __attribute__((ext_vector_type(4))) float f32x4;
typedef __attribute__((ext_vector_type(2))) float f32x2;

// float -> bf16 (RNE)
__device__ __forceinline__ unsigned short f2bf(float f) {
    unsigned int u = __float_as_uint(f);
    u = (u + 0x7FFFu + ((u >> 16) & 1u)) >> 16;
    return (unsigned short)u;
}
__device__ __forceinline__ f32x2 bf2(unsigned int u) {
    return (f32x2){__uint_as_float(u << 16), __uint_as_float(u & 0xFFFF0000u)};
}

// ---- Kernel W: pack [Wl|Wr] into per-lane MFMA B-fragment layout (bf16),
//      [bl|br] into bp[512]; blocks >=130 zero cnt (fused memset).
__global__ __launch_bounds__(256) void k_wpack(
    const float* __restrict__ Wl, const float* __restrict__ bl,
    const float* __restrict__ Wr, const float* __restrict__ br,
    unsigned short* __restrict__ wp, float* __restrict__ bp,
    int* __restrict__ zbase)
{
    if (blockIdx.x >= 130) {
        const int i = (blockIdx.x - 130) * 256 + threadIdx.x;
        if (i < NN) zbase[i] = 0;
        return;
    }
    const int tid = blockIdx.x * 256 + threadIdx.x;
    if (tid < 32768) {
        const int j  = tid & 7;
        const int l  = (tid >> 3) & 63;
        const int s  = (tid >> 9) & 1;
        const int ct = tid >> 10;
        const int col = ct * 16 + (l & 15);
        const int kk  = s * 32 + ((l >> 4) << 3) + j;
        const float w = (col < 256) ? Wl[kk * 256 + col] : Wr[kk * 256 + (col - 256)];
        wp[tid] = f2bf(w);
    } else if (tid < 32768 + 512) {
        const int c = tid - 32768;
        bp[c] = (c < 256) ? bl[c] : br[c - 256];
    }
}

// ---- Fused prep: blocks [0,625) = MFMA lin (LDS-staged coalesced stores);
//      blocks [625,1250) = edge scatter (no asum — self-loop attr computed
//      in-wave in k_gat).  xl/xr layout: row-major [b*NN+n][256] bf16.
__global__ __launch_bounds__(256) void k_pre(
    const float* __restrict__ x, const unsigned short* __restrict__ wp,
    const float* __restrict__ bp,
    unsigned short* __restrict__ xl, unsigned short* __restrict__ xr,
    const int* __restrict__ ei, const float* __restrict__ ea,
    int* __restrict__ cnt, int* __restrict__ cmeta)
{
    __shared__ unsigned short st[64][264];   // 33.8 KB; pad -> 16B-aligned rows

    if (blockIdx.x >= 625) {
        // ---- edge scatter into padded CSR; packed (src<<16 | bf16(attr)) ----
        const int e = (blockIdx.x - 625) * 256 + threadIdx.x;   // exactly EE threads
        const int   sn = ei[e];
        const int   d  = ei[EE + e];
        const float a  = ea[e];
        const int pos  = atomicAdd(&cnt[d], 1);
        if (pos < CAPE - 1)
            cmeta[d * CAPE + pos] = (sn << 16) | (int)f2bf(a);
        return;
    }
    // ---- MFMA lin: [40000 x 64] @ [64 x 512] -> xl/xr bf16, row-major.
    const int t = threadIdx.x;
    const int w = t >> 6, l = t & 63;
    const int row0 = blockIdx.x * 64 + w * 16;
    const int arow = row0 + (l & 15);
    const float* xp = x + (size_t)arow * 64 + ((l >> 4) << 3);

    bf16x8 a[2];
#pragma unroll
    for (int s = 0; s < 2; ++s) {
        const float4 lo = *reinterpret_cast<const float4*>(xp + s * 32);
        const float4 hi = *reinterpret_cast<const float4*>(xp + s * 32 + 4);
        union { bf16x8 v; unsigned short u[8]; } tt;
        tt.u[0] = f2bf(lo.x); tt.u[1] = f2bf(lo.y); tt.u[2] = f2bf(lo.z); tt.u[3] = f2bf(lo.w);
        tt.u[4] = f2bf(hi.x); tt.u[5] = f2bf(hi.y); tt.u[6] = f2bf(hi.z); tt.u[7] = f2bf(hi.w);
        a[s] = tt.v;
    }
    const int colb = l & 15;
    const int rsub = (l >> 4) << 2;

    for (int h = 0; h < 2; ++h) {          // h=0: xl (ct 0..15), h=1: xr (ct 16..31)
        for (int g4 = 0; g4 < 4; ++g4) {
            f32x4 acc[4] = {{0.f,0.f,0.f,0.f},{0.f,0.f,0.f,0.f},
                            {0.f,0.f,0.f,0.f},{0.f,0.f,0.f,0.f}};
#pragma unroll
            for (int c = 0; c < 4; ++c) {
                const int ct = h * 16 + g4 * 4 + c;
                const bf16x8 b0 = *reinterpret_cast<const bf16x8*>(wp + (((ct * 2 + 0) * 64 + l) << 3));
                const bf16x8 b1 = *reinterpret_cast<const bf16x8*>(wp + (((ct * 2 + 1) * 64 + l) << 3));
                acc[c] = __builtin_amdgcn_mfma_f32_16x16x32_bf16(a[0], b0, acc[c], 0, 0, 0);
                acc[c] = __builtin_amdgcn_mfma_f32_16x16x32_bf16(a[1], b1, acc[c], 0, 0, 0);
            }
#pragma unroll
            for (int c = 0; c < 4; ++c) {
                const int colh = (g4 * 4 + c) * 16 + colb;   // 0..255 within half
                const float bv = bp[h * 256 + colh];
#pragma unroll
                for (int r = 0; r < 4; ++r)
                    st[w * 16 + rsub + r][colh] = f2bf(acc[c][r] + bv);
            }
        }
        __syncthreads();
        // coalesced write-out: each row = 512 B contiguous (32 lanes x 16 B)
        unsigned short* __restrict__ dstb = h ? xr : xl;
        for (int rr = (t >> 5); rr < 64; rr += 8) {
            const size_t row = blockIdx.x * 64 + rr;         // row = b*NN + n
            const uint4 v = *reinterpret_cast<const uint4*>(&st[rr][(t & 31) * 8]);
            *reinterpret_cast<uint4*>(dstb + (row << 8) + (t & 31) * 8) = v;
        }
        __syncthreads();
    }
}

// ------ Kernel C: one wave per NODE, all 4 batches; 4-slot pipeline. ------
// grid = NN blocks x 64 threads. Lane ln = b*16 + cg: batch b = ln>>4,
// channels [cg*16, cg*16+16) of batch b. Per edge: wave loads 4 rows (2 KB,
// 32 B/lane, coalesced); 1 readlane serves all 4 batches; butterfly over the
// 8 lanes of each (b, head) group; exp2 with pre-scaled att; every (b,ch) is
// lane-owned -> no merges, no LDS, no barriers. Self-loop attr computed
// in-wave (sum of lane-resident attrs).
__global__ __launch_bounds__(64) void k_gat(
    const unsigned short* __restrict__ xl, const unsigned short* __restrict__ xr,
    const int* __restrict__ cnt, const int* __restrict__ cmeta,
    const float* __restrict__ We, const float* __restrict__ att,
    const float* __restrict__ bias, float* __restrict__ outp)
{
    const int ln = threadIdx.x;
    const int n  = blockIdx.x;
    const int b  = ln >> 4;
    const int cg = ln & 15;
    const int ch0 = cg << 4;

    int dg0 = cnt[n];
    if (dg0 > CAPE - 1) dg0 = CAPE - 1;   // statistically impossible to clamp
    const int dg = __builtin_amdgcn_readfirstlane(dg0);
    int mp = cmeta[n * CAPE + ln];        // lane i = edge i (src<<16 | bf16 attr)

    // self-loop attr = mean of incoming attrs, computed in-wave
    {
        float av = (ln < dg) ? __uint_as_float(((unsigned int)mp) << 16) : 0.f;
#pragma unroll
        for (int m = 1; m <= 32; m <<= 1) av += __shfl_xor(av, m);
        const float mean = av / fmaxf((float)dg, 1.0f);
        if (ln == dg) mp = (n << 16) | (int)f2bf(mean);
    }
    const int ntot = dg + 1;

    // per-lane constants: channels [ch0, ch0+16) of batch b as 8 f32x2
    f32x2 we2[8], at2[8], xr2[8], acc2[8];
    {
        const float4* Wp = reinterpret_cast<const float4*>(We + ch0);
        const float4* Ap = reinterpret_cast<const float4*>(att + ch0);
        const float l2e = 1.44269504f;    // pre-scale att so exp2 suffices
#pragma unroll
        for (int j = 0; j < 4; ++j) {
            const float4 w4 = Wp[j], a4 = Ap[j];
            we2[2*j+0] = (f32x2){w4.x, w4.y};
            we2[2*j+1] = (f32x2){w4.z, w4.w};
            at2[2*j+0] = (f32x2){a4.x * l2e, a4.y * l2e};
            at2[2*j+1] = (f32x2){a4.z * l2e, a4.w * l2e};
        }
        const uint4* Xp = reinterpret_cast<const uint4*>(
            xr + (((size_t)(b * NN + n)) << 8) + ch0);
        const uint4 r0 = Xp[0], r1 = Xp[1];
        xr2[0] = bf2(r0.x); xr2[1] = bf2(r0.y); xr2[2] = bf2(r0.z); xr2[3] = bf2(r0.w);
        xr2[4] = bf2(r1.x); xr2[5] = bf2(r1.y); xr2[6] = bf2(r1.z); xr2[7] = bf2(r1.w);
    }
    const f32x2 km1 = {SLOPEK - 1.f, SLOPEK - 1.f};
    const f32x2 z2  = {0.f, 0.f};
#pragma unroll
    for (int k = 0; k < 8; ++k) acc2[k] = z2;
    float sh = 0.f;

    // per-lane gather base: batch table + channel offset
    const unsigned short* __restrict__ xlp =
        xl + (((size_t)b * NN) << 8) + ch0;

    // pipeline slots (registers, statically indexed)
    uint4 A0, B0, A1, B1, A2, B2, A3, B3;
    float ea0, ea1, ea2, ea3;

#define LOADSLOT(S, IDX) do { \
        const int ii_ = (IDX); \
        const int ic_ = ii_ < dg ? ii_ : dg; \
        const int mm_ = __builtin_amdgcn_readlane(mp, ic_); \
        ea##S = __uint_as_float(((unsigned int)mm_) << 16); \
        const unsigned short* p_ = xlp + ((size_t)(mm_ >> 16) << 8); \
        A##S = *reinterpret_cast<const uint4*>(p_); \
        B##S = *reinterpret_cast<const uint4*>(p_ + 8); \
    } while (0)

    auto edgeC = [&](const uint4& A, const uint4& Bv, float a0) {
        f32x2 xv2[8];
        xv2[0] = bf2(A.x);  xv2[1] = bf2(A.y);  xv2[2] = bf2(A.z);  xv2[3] = bf2(A.w);
        xv2[4] = bf2(Bv.x); xv2[5] = bf2(Bv.y); xv2[6] = bf2(Bv.z); xv2[7] = bf2(Bv.w);

        const f32x2 a02 = {a0, a0};
        f32x2 qa = z2, qb = z2;
#pragma unroll
        for (int j = 0; j < 8; ++j) {
            f32x2 s = xv2[j] + xr2[j];                           // v_pk_add_f32
            f32x2 v = __builtin_elementwise_fma(a02, we2[j], s); // v_pk_fma_f32
            f32x2 vm = __builtin_elementwise_min(v, z2);         // v_pk_min_f32
            v = __builtin_elementwise_fma(km1, vm, v);
            if (j & 1) qb = __builtin_elementwise_fma(v, at2[j], qb);
            else       qa = __builtin_elementwise_fma(v, at2[j], qa);
        }
        const f32x2 q2 = qa + qb;
        float p = q2.x + q2.y;
        // reduce over the 8 lanes of this (b, head) group
        p += __shfl_xor(p, 1);
        p += __shfl_xor(p, 2);
        p += __shfl_xor(p, 4);
        const float e = exp2f(p);     // att pre-scaled by log2(e)
        sh += e;
        const f32x2 e2 = {e, e};
#pragma unroll
        for (int j = 0; j < 8; ++j)
            acc2[j] = __builtin_elementwise_fma(e2, xv2[j], acc2[j]);
    };

    // prologue: edges 0..2 (clamped duplicates harmless)
    LOADSLOT(0, 0);
    LOADSLOT(1, 1);
    LOADSLOT(2, 2);

    int i = 0;
    for (; i + 3 < ntot; i += 4) {
        LOADSLOT(3, i + 3); edgeC(A0, B0, ea0);
        LOADSLOT(0, i + 4); edgeC(A1, B1, ea1);
        LOADSLOT(1, i + 5); edgeC(A2, B2, ea2);
        LOADSLOT(2, i + 6); edgeC(A3, B3, ea3);
    }
    // tail (slots 0..2 hold edges i..i+2); wave-uniform branches
    if (i     < ntot) edgeC(A0, B0, ea0);
    if (i + 1 < ntot) edgeC(A1, B1, ea1);
    if (i + 2 < ntot) edgeC(A2, B2, ea2);
#undef LOADSLOT

    // ---- epilogue: every (b, ch) owned by exactly this lane ----
    const float inv = 1.0f / sh;
    float* ob = outp + (((size_t)(b * NN + n)) << 8) + ch0;
    const float4* Bp = reinterpret_cast<const float4*>(bias + ch0);
#pragma unroll
    for (int j = 0; j < 4; ++j) {
        const float4 b4 = Bp[j];
        float4 o;
        o.x = fmaf(acc2[2*j+0].x, inv, b4.x);
        o.y = fmaf(acc2[2*j+0].y, inv, b4.y);
        o.z = fmaf(acc2[2*j+1].x, inv, b4.z);
        o.w = fmaf(acc2[2*j+1].y, inv, b4.w);
        reinterpret_cast<float4*>(ob)[j] = o;
    }
}

// -------------------------- launcher --------------------------
extern "C" void kernel_launch(void* const* d_in, const int* in_sizes, int n_in,
                              void* d_out, int out_size, void* d_ws, size_t ws_size,
                              hipStream_t stream)
{
    (void)in_sizes; (void)n_in; (void)out_size; (void)ws_size;
    const float* x    = (const float*)d_in[0];
    const int*   ei   = (const int*)d_in[1];
    const float* ea   = (const float*)d_in[2];
    const float* Wl   = (const float*)d_in[3];
    const float* bl   = (const float*)d_in[4];
    const float* Wr   = (const float*)d_in[5];
    const float* br   = (const float*)d_in[6];
    const float* We   = (const float*)d_in[7];
    const float* att  = (const float*)d_in[8];
    const float* bias = (const float*)d_in[9];
    float* outp = (float*)d_out;

    const size_t R = (size_t)BQ * NN;     // 40000 rows
    unsigned short* xl16 = (unsigned short*)d_ws;          // R*HC bf16
    unsigned short* xr16 = xl16 + R * HC;                  // R*HC bf16
    int*   cnt   = (int*)(xr16 + R * HC);                  // NN ints
    int*   cmeta = cnt + NN;                               // NN*CAPE int
    unsigned short* wp = (unsigned short*)(cmeta + (size_t)NN * CAPE);  // 32768 bf16
    float* bp    = (float*)(wp + 32768);                   // 512 f32

    // k_wpack also zeroes cnt (blocks >= 130)
    k_wpack<<<130 + (NN + 255) / 256, 256, 0, stream>>>(Wl, bl, Wr, br, wp, bp, cnt);
    k_pre  <<<1250, 256, 0, stream>>>(x, wp, bp, xl16, xr16,
                                      ei, ea, cnt, cmeta);
    k_gat  <<<NN, 64, 0, stream>>>(xl16, xr16, cnt, cmeta,
                                   We, att, bias, outp);
}